// Round 10
// baseline (147.213 us; speedup 1.0000x reference)
//
#include <hip/hip_runtime.h>
#include <stdint.h>

#define NN 8192   // nodes
#define NE 8192   // edges
#define DIM 128
#define NL 17
#define NW 256            // bitmap words per edge (8192/32)
#define LIST_MAX 512      // max degree supported (observed ~82 +/- 9)

// ---- workspace layout (bytes) ----
#define WS_BMT    0ull                              // 8 MB  (bmT[e][256] words)
#define WS_COLSUM (8ull << 20)                      // 64 KB (128 x 128 f32)
#define WS_C0E    ((8ull << 20) + (64ull << 10))    // 8.5 KB

// Bit-compress incidence into EDGE-MAJOR bitmap: bmT[e][w] bit b = 
// (inc[w*32+b][e] != 0). Grid 512 = 8 e-tiles x 64 k-tiles. Each thread owns
// 4 edges (one float4 column) x 128 k-rows; 128 coalesced float4 loads
// (16B/lane), 16 bit-words in registers (all static indexing), 4x16B writes.
// No atomics, no LDS, deterministic. Only reader of the 268 MB incidence.
__global__ __launch_bounds__(256) void k_scan(const float4* __restrict__ inc4,
                                              uint32_t* __restrict__ bmT) {
  const int t = threadIdx.x;
  const int et = blockIdx.x & 7;          // e-tile: 1024 edges
  const int kt = blockIdx.x >> 3;         // k-tile: 128 rows (4 words)
  const int e4 = et * 256 + t;            // float4 column index
  const int k0 = kt * 128;
  uint32_t bw[4][4];                      // [word][edge-component]
#pragma unroll
  for (int wi = 0; wi < 4; ++wi)
#pragma unroll
    for (int c = 0; c < 4; ++c) bw[wi][c] = 0;
#pragma unroll
  for (int wi = 0; wi < 4; ++wi) {
#pragma unroll
    for (int kb = 0; kb < 32; ++kb) {
      float4 v = inc4[(size_t)(k0 + wi * 32 + kb) * (NE / 4) + e4];
      bw[wi][0] |= (v.x != 0.f ? 1u : 0u) << kb;
      bw[wi][1] |= (v.y != 0.f ? 1u : 0u) << kb;
      bw[wi][2] |= (v.z != 0.f ? 1u : 0u) << kb;
      bw[wi][3] |= (v.w != 0.f ? 1u : 0u) << kb;
    }
  }
#pragma unroll
  for (int c = 0; c < 4; ++c) {
    int e = e4 * 4 + c;
    uint4* dst = (uint4*)(bmT + (size_t)e * NW + kt * 4);
    *dst = make_uint4(bw[0][c], bw[1][c], bw[2][c], bw[3][c]);
  }
}

// Column partial sums of x: 128 blocks x 64 rows each.
__global__ __launch_bounds__(128) void k_colsum(const float* __restrict__ x,
                                                float* __restrict__ colsum) {
  const int t = threadIdx.x;
  const int b = blockIdx.x;
  float s = 0.f;
  const float* p = x + (size_t)b * 64 * DIM + t;
#pragma unroll 8
  for (int n = 0; n < 64; ++n) s += p[(size_t)n * DIM];
  colsum[b * DIM + t] = s;
}

// c0e[l][j] = x0 @ W[0,l] + B[l]; c0e[1] doubles as node-side constant.
__global__ __launch_bounds__(128) void k_c0e(const float* __restrict__ colsum,
                                             const float* __restrict__ W,
                                             const float* __restrict__ Bb,
                                             float* __restrict__ c0e) {
  __shared__ float x0[DIM];
  const int j = threadIdx.x;
  float s = 0.f;
  for (int b = 0; b < 128; ++b) s += colsum[b * DIM + j];
  x0[j] = s * (1.0f / NN);
  __syncthreads();
  const int l = blockIdx.x;
  const float* W0l = W + (size_t)l * DIM * DIM;
  float acc = Bb[l * DIM + j];
#pragma unroll 8
  for (int i = 0; i < DIM; ++i) acc += x0[i] * W0l[(size_t)i * DIM + j];
  c0e[l * DIM + j] = acc;
}

// Fused edge kernel: one block per edge, 128 threads (thread = dim d).
// 1) read this edge's 256 bitmap words (1 KB contiguous),
// 2) LDS prefix-scan -> ordered incident-node list (ascending k),
// 3) gather+sum x rows in exact f32 (L2-resident), normalize,
// 4) matvec with W[1,order] + c0e[order] (proven edge2 loop), write out.
__global__ __launch_bounds__(128) void k_edgeF(const uint32_t* __restrict__ bmT,
                                               const float* __restrict__ x,
                                               const int* __restrict__ orders,
                                               const float* __restrict__ norm,
                                               const float* __restrict__ W,
                                               const float* __restrict__ c0e,
                                               float* __restrict__ out_e) {
  __shared__ int cnt[128];
  __shared__ unsigned short list[LIST_MAX];
  __shared__ float xl[DIM];
  const int t = threadIdx.x;
  const int e = blockIdx.x;

  const uint2 ww = *(const uint2*)(bmT + (size_t)e * NW + 2 * t);
  const int own = __popc(ww.x) + __popc(ww.y);
  cnt[t] = own;
  __syncthreads();
  // Hillis-Steele inclusive scan over 128 entries
  for (int off = 1; off < 128; off <<= 1) {
    int v = (t >= off) ? cnt[t - off] : 0;
    __syncthreads();
    cnt[t] += v;
    __syncthreads();
  }
  int p = cnt[t] - own;           // exclusive prefix
  uint32_t m = ww.x;
  while (m) {
    int b = __ffs(m) - 1;
    if (p < LIST_MAX) list[p] = (unsigned short)(2 * t * 32 + b);
    ++p; m &= m - 1;
  }
  m = ww.y;
  while (m) {
    int b = __ffs(m) - 1;
    if (p < LIST_MAX) list[p] = (unsigned short)((2 * t + 1) * 32 + b);
    ++p; m &= m - 1;
  }
  __syncthreads();
  int total = cnt[127];
  if (total > LIST_MAX) total = LIST_MAX;

  float acc = 0.f;
#pragma unroll 4
  for (int i = 0; i < total; ++i) {
    int n = list[i];                       // LDS broadcast
    acc += x[(size_t)n * DIM + t];         // coalesced 512B row (L2-hot)
  }
  xl[t] = acc / norm[e];
  __syncthreads();

  const int l = orders[e];
  const float* W1l = W + (size_t)(NL + l) * DIM * DIM;
  float o = c0e[l * DIM + t];
#pragma unroll 8
  for (int i = 0; i < DIM; ++i) o += xl[i] * W1l[(size_t)i * DIM + t];
  out_e[(size_t)e * DIM + t] = o;
}

// Node side: out_v[n] = c0e[1] + x[n] @ W[1,1]. 4x4 register tile per thread.
__global__ __launch_bounds__(256) void k_node(const float* __restrict__ x,
                                              const float* __restrict__ W,
                                              const float* __restrict__ c0e,
                                              float* __restrict__ out_v) {
  __shared__ float xr[32][DIM];
  const int t = threadIdx.x;
  const int row0 = blockIdx.x * 32;
  for (int i = t; i < 32 * DIM; i += 256)
    xr[i >> 7][i & 127] = x[(size_t)row0 * DIM + i];
  const int tx = t & 31;
  const int ty = t >> 5;
  const float4* W4 = (const float4*)(W + (size_t)(NL + 1) * DIM * DIM);
  const float4 cv = ((const float4*)(c0e + DIM))[tx];
  float4 o0 = cv, o1 = cv, o2 = cv, o3 = cv;
  __syncthreads();
#pragma unroll 4
  for (int k = 0; k < DIM; ++k) {
    float4 w = W4[k * 32 + tx];
    float a0 = xr[ty * 4 + 0][k];
    float a1 = xr[ty * 4 + 1][k];
    float a2 = xr[ty * 4 + 2][k];
    float a3 = xr[ty * 4 + 3][k];
    o0.x += a0 * w.x; o0.y += a0 * w.y; o0.z += a0 * w.z; o0.w += a0 * w.w;
    o1.x += a1 * w.x; o1.y += a1 * w.y; o1.z += a1 * w.z; o1.w += a1 * w.w;
    o2.x += a2 * w.x; o2.y += a2 * w.y; o2.z += a2 * w.z; o2.w += a2 * w.w;
    o3.x += a3 * w.x; o3.y += a3 * w.y; o3.z += a3 * w.z; o3.w += a3 * w.w;
  }
  float4* out4 = (float4*)(out_v + (size_t)(row0 + ty * 4) * DIM);
  out4[0 * 32 + tx] = o0;
  out4[1 * 32 + tx] = o1;
  out4[2 * 32 + tx] = o2;
  out4[3 * 32 + tx] = o3;
}

extern "C" void kernel_launch(void* const* d_in, const int* in_sizes, int n_in,
                              void* d_out, int out_size, void* d_ws, size_t ws_size,
                              hipStream_t stream) {
  const float* x      = (const float*)d_in[0];
  const float* inc    = (const float*)d_in[1];
  const int*   orders = (const int*)d_in[2];
  const float* norm   = (const float*)d_in[3];
  const float* W      = (const float*)d_in[4];
  const float* Bb     = (const float*)d_in[5];
  float* out_v = (float*)d_out;
  float* out_e = (float*)d_out + (size_t)NN * DIM;

  char* ws = (char*)d_ws;
  uint32_t* bmT   = (uint32_t*)(ws + WS_BMT);
  float* colsum   = (float*)(ws + WS_COLSUM);
  float* c0e      = (float*)(ws + WS_C0E);

  k_scan<<<512, 256, 0, stream>>>((const float4*)inc, bmT);
  k_colsum<<<128, 128, 0, stream>>>(x, colsum);
  k_c0e<<<NL, 128, 0, stream>>>(colsum, W, Bb, c0e);
  k_edgeF<<<NE, 128, 0, stream>>>(bmT, x, orders, norm, W, c0e, out_e);
  k_node<<<NN / 32, 256, 0, stream>>>(x, W, c0e, out_v);
}

// Round 11
// 127.188 us; speedup vs baseline: 1.1574x; 1.1574x over previous
//
#include <hip/hip_runtime.h>
#include <stdint.h>

#define NN 8192   // nodes
#define NE 8192   // edges
#define DIM 128
#define NL 17
#define SPLITK 8
#define KCHUNK (NN / SPLITK)   // 1024
#define NIT (KCHUNK / 32)      // 32
#define EPB 8                  // edges per block in k_edgeG

typedef float f32x4 __attribute__((ext_vector_type(4)));
typedef short short8 __attribute__((ext_vector_type(8)));

// ---- workspace layout (bytes) ----
#define WS_XHI    0ull                              // 2 MB  (xT blocked bf16)
#define WS_COLSUM (4ull << 20)                      // 64 KB (128 x 128 f32)
#define WS_C0E    ((4ull << 20) + (64ull << 10))    // 8.5 KB
#define WS_ELIST  ((4ull << 20) + (80ull << 10))    // 32 KB (8192 int)
#define WS_PART   (8ull << 20)                      // 32 MB (SPLITK x E x D f32)

#define GPTR(p) ((const __attribute__((address_space(1))) uint32_t*)(p))
#define LPTR(p) ((__attribute__((address_space(3))) uint32_t*)(p))

// Round-to-nearest-even f32 -> bf16 bits.
__device__ __forceinline__ uint16_t f32_to_bf16(float v) {
  uint32_t u = __builtin_bit_cast(uint32_t, v);
  u += 0x7fffu + ((u >> 16) & 1u);
  return (uint16_t)(u >> 16);
}

// Prep: column sums of x (for x0), and x transposed into k-blocked bf16:
// xhi[kblk][d][kk] with kblk = k/32, kk = k%32. 128 blocks x 64 nodes.
__global__ __launch_bounds__(256) void k_prep(const float* __restrict__ x,
                                              uint16_t* __restrict__ xhi,
                                              float* __restrict__ colsum) {
  __shared__ float xs[64][129];
  const int t = threadIdx.x;
  const int b = blockIdx.x;  // nodes b*64 .. b*64+63
  const float4* xg = (const float4*)(x + (size_t)b * 64 * DIM);
  for (int r = 0; r < 8; ++r) {
    int f = t + r * 256;           // float4 index within tile
    float4 v = xg[f];
    int n = f >> 5;
    int d0 = (f & 31) * 4;
    xs[n][d0] = v.x; xs[n][d0 + 1] = v.y; xs[n][d0 + 2] = v.z; xs[n][d0 + 3] = v.w;
  }
  __syncthreads();
  if (t < 128) {
    float s = 0.f;
    for (int n = 0; n < 64; ++n) s += xs[n][t];
    colsum[b * DIM + t] = s;
  }
  // 1024 16B chunks: q = [kb(1)][d(7)][c(2)]
  for (int r = 0; r < 4; ++r) {
    int q = t + r * 256;
    int c = q & 3;
    int d = (q >> 2) & 127;
    int kb = q >> 9;
    int kk0 = c * 8;
    uint32_t w[4];
    for (int j = 0; j < 4; ++j) {
      uint16_t h0 = f32_to_bf16(xs[kb * 32 + kk0 + 2 * j][d]);
      uint16_t h1 = f32_to_bf16(xs[kb * 32 + kk0 + 2 * j + 1][d]);
      w[j] = (uint32_t)h0 | ((uint32_t)h1 << 16);
    }
    int kblk = b * 2 + kb;
    uint16_t* dst = xhi + ((size_t)(kblk * 128 + d)) * 32 + kk0;
    *(uint4*)dst = make_uint4(w[0], w[1], w[2], w[3]);
  }
}

// c0e[l][j] = x0 @ W[0,l] + B[l]; c0e[1] doubles as node-side constant.
__global__ __launch_bounds__(128) void k_c0e(const float* __restrict__ colsum,
                                             const float* __restrict__ W,
                                             const float* __restrict__ Bb,
                                             float* __restrict__ c0e) {
  __shared__ float x0[DIM];
  const int j = threadIdx.x;
  float s = 0.f;
  for (int b = 0; b < 128; ++b) s += colsum[b * DIM + j];
  x0[j] = s * (1.0f / NN);
  __syncthreads();
  const int l = blockIdx.x;
  const float* W0l = W + (size_t)l * DIM * DIM;
  float acc = Bb[l * DIM + j];
#pragma unroll 8
  for (int i = 0; i < DIM; ++i) acc += x0[i] * W0l[(size_t)i * DIM + j];
  c0e[l * DIM + j] = acc;
}

// Bucket edges by order into elist (single block). Slot order within a
// bucket is non-deterministic (LDS atomics) but every edge's output value
// is independent of its slot -> outputs deterministic. elist is fully
// overwritten every call (every edge written exactly once).
__global__ __launch_bounds__(256) void k_count(const int* __restrict__ orders,
                                               int* __restrict__ elist) {
  __shared__ int hist[NL], cur[NL];
  const int t = threadIdx.x;
  if (t < NL) hist[t] = 0;
  __syncthreads();
  for (int i = t; i < NE; i += 256) atomicAdd(&hist[orders[i]], 1);
  __syncthreads();
  if (t == 0) {
    int run = 0;
    for (int l = 0; l < NL; ++l) { cur[l] = run; run += hist[l]; }
  }
  __syncthreads();
  for (int i = t; i < NE; i += 256) {
    int pos = atomicAdd(&cur[orders[i]], 1);
    elist[pos] = i;
  }
}

// Big MFMA GEMM (exact round-7 form): part[s][e][d] = sum_k inc[k][e]*xhi[k][d].
// Double-buffered B via global_load_lds(16B), A-register prefetch one
// iteration ahead, one __syncthreads per iteration.
__global__ __launch_bounds__(256, 2) void k_gemm(const float* __restrict__ inc,
                                                 const uint16_t* __restrict__ xhi,
                                                 float* __restrict__ part) {
  __shared__ uint16_t Bs[2][4096];   // 8 KB per buffer
  const int t = threadIdx.x;
  const int mb = blockIdx.x & 63;
  const int s = blockIdx.x >> 6;
  const int e0 = mb * 128;
  const int w = t >> 6;
  const int lane = t & 63;
  const int lm = lane & 15;
  const int lk = lane >> 4;          // 0..3
  const int kbase = s * KCHUNK;
  const int kb0 = kbase >> 5;        // first kblk

  f32x4 acc[2][8];
#pragma unroll
  for (int a = 0; a < 2; ++a)
#pragma unroll
    for (int b = 0; b < 8; ++b) acc[a][b] = (f32x4){0.f, 0.f, 0.f, 0.f};

  const char* hbase = (const char*)xhi;

#define STAGE(buf, kblk) { \
    const char* hsrc = hbase + (size_t)(kblk) * 8192; \
    char* dbase = (char*)&Bs[buf][0]; \
    _Pragma("unroll") \
    for (int j = 0; j < 2; ++j) { \
      int q = w + 4 * j; \
      __builtin_amdgcn_global_load_lds(GPTR(hsrc + q * 1024 + lane * 16), \
                                       LPTR(dbase + q * 1024), 16, 0, 0); \
    } }

#define LOADA(u, it) { \
    const int k0_ = kbase + (it) * 32; \
    _Pragma("unroll") \
    for (int fm = 0; fm < 2; ++fm) { \
      const float* ap = inc + (size_t)(k0_ + lk * 8) * NE + (e0 + w * 32 + fm * 16 + lm); \
      _Pragma("unroll") \
      for (int j = 0; j < 8; ++j) \
        u[fm][j] = __builtin_bit_cast(uint32_t, ap[(size_t)j * NE]); \
    } }

#define COMPUTE(buf, u) { \
    short8 afr[2]; \
    _Pragma("unroll") \
    for (int fm = 0; fm < 2; ++fm) { \
      union { uint32_t w4[4]; short8 s8; } pk; \
      _Pragma("unroll") \
      for (int j = 0; j < 4; ++j) \
        pk.w4[j] = (u[fm][2 * j + 1] & 0xffff0000u) | (u[fm][2 * j] >> 16); \
      afr[fm] = pk.s8; \
    } \
    _Pragma("unroll") \
    for (int fn = 0; fn < 8; ++fn) { \
      int n = fn * 16 + lm; \
      short8 bh = *(const short8*)&Bs[buf][n * 32 + lk * 8]; \
      acc[0][fn] = __builtin_amdgcn_mfma_f32_16x16x32_bf16(afr[0], bh, acc[0][fn], 0, 0, 0); \
      acc[1][fn] = __builtin_amdgcn_mfma_f32_16x16x32_bf16(afr[1], bh, acc[1][fn], 0, 0, 0); \
    } }

  uint32_t ua[2][8], ub[2][8];
  STAGE(0, kb0);
  LOADA(ua, 0);
  __syncthreads();               // Bs[0] staged, ua ready

  for (int it2 = 0; it2 < NIT; it2 += 2) {
    if (it2 + 1 < NIT) { STAGE(1, kb0 + it2 + 1); LOADA(ub, it2 + 1); }
    COMPUTE(0, ua);
    __syncthreads();
    if (it2 + 2 < NIT) { STAGE(0, kb0 + it2 + 2); LOADA(ua, it2 + 2); }
    COMPUTE(1, ub);
    __syncthreads();
  }

  float* pbase = part + (size_t)s * NE * DIM;
#pragma unroll
  for (int fm = 0; fm < 2; ++fm)
#pragma unroll
    for (int fn = 0; fn < 8; ++fn)
#pragma unroll
      for (int r = 0; r < 4; ++r) {
        int e = e0 + w * 32 + fm * 16 + lk * 4 + r;
        int d = fn * 16 + lm;
        pbase[(size_t)e * DIM + d] = acc[fm][fn][r];
      }
#undef STAGE
#undef LOADA
#undef COMPUTE
}

// Order-grouped edge kernel: 8 same-order edges per block (via elist), so
// each W[1,l] row is loaded ONCE and broadcast to 8 register-FMAs -> W L2
// traffic /8. Per-edge arithmetic bit-identical to the old k_edge2 (split
// sum ascending s, /norm, matvec ascending i, c0e-seeded). Rare mixed-order
// boundary blocks take the per-edge-W fallback.
__global__ __launch_bounds__(128) void k_edgeG(const float* __restrict__ part,
                                               const int* __restrict__ elist,
                                               const int* __restrict__ orders,
                                               const float* __restrict__ norm,
                                               const float* __restrict__ W,
                                               const float* __restrict__ c0e,
                                               float* __restrict__ out_e) {
  __shared__ float xl[EPB][DIM];
  __shared__ int el[EPB], lord[EPB];
  const int t = threadIdx.x;
  if (t < EPB) {
    int e = elist[blockIdx.x * EPB + t];
    el[t] = e;
    lord[t] = orders[e];
  }
  __syncthreads();
#pragma unroll
  for (int ei = 0; ei < EPB; ++ei) {
    const int e = el[ei];
    float s = 0.f;
#pragma unroll
    for (int k = 0; k < SPLITK; ++k)
      s += part[(size_t)k * NE * DIM + (size_t)e * DIM + t];
    xl[ei][t] = s / norm[e];
  }
  __syncthreads();

  const int l0 = lord[0];
  bool uni = true;
#pragma unroll
  for (int ei = 1; ei < EPB; ++ei) uni = uni && (lord[ei] == l0);

  float o[EPB];
#pragma unroll
  for (int ei = 0; ei < EPB; ++ei) o[ei] = c0e[lord[ei] * DIM + t];

  if (uni) {
    const float* W1 = W + (size_t)(NL + l0) * DIM * DIM + t;
#pragma unroll 4
    for (int i = 0; i < DIM; ++i) {
      float wv = W1[(size_t)i * DIM];
#pragma unroll
      for (int ei = 0; ei < EPB; ++ei) o[ei] += xl[ei][i] * wv;
    }
  } else {
    for (int i = 0; i < DIM; ++i) {
#pragma unroll
      for (int ei = 0; ei < EPB; ++ei)
        o[ei] += xl[ei][i] *
                 W[(size_t)(NL + lord[ei]) * DIM * DIM + (size_t)i * DIM + t];
    }
  }
#pragma unroll
  for (int ei = 0; ei < EPB; ++ei)
    out_e[(size_t)el[ei] * DIM + t] = o[ei];
}

// Node side: out_v[n] = c0e[1] + x[n] @ W[1,1]. 4x4 register tile per thread.
__global__ __launch_bounds__(256) void k_node(const float* __restrict__ x,
                                              const float* __restrict__ W,
                                              const float* __restrict__ c0e,
                                              float* __restrict__ out_v) {
  __shared__ float xr[32][DIM];
  const int t = threadIdx.x;
  const int row0 = blockIdx.x * 32;
  for (int i = t; i < 32 * DIM; i += 256)
    xr[i >> 7][i & 127] = x[(size_t)row0 * DIM + i];
  const int tx = t & 31;
  const int ty = t >> 5;
  const float4* W4 = (const float4*)(W + (size_t)(NL + 1) * DIM * DIM);
  const float4 cv = ((const float4*)(c0e + DIM))[tx];
  float4 o0 = cv, o1 = cv, o2 = cv, o3 = cv;
  __syncthreads();
#pragma unroll 4
  for (int k = 0; k < DIM; ++k) {
    float4 w = W4[k * 32 + tx];
    float a0 = xr[ty * 4 + 0][k];
    float a1 = xr[ty * 4 + 1][k];
    float a2 = xr[ty * 4 + 2][k];
    float a3 = xr[ty * 4 + 3][k];
    o0.x += a0 * w.x; o0.y += a0 * w.y; o0.z += a0 * w.z; o0.w += a0 * w.w;
    o1.x += a1 * w.x; o1.y += a1 * w.y; o1.z += a1 * w.z; o1.w += a1 * w.w;
    o2.x += a2 * w.x; o2.y += a2 * w.y; o2.z += a2 * w.z; o2.w += a2 * w.w;
    o3.x += a3 * w.x; o3.y += a3 * w.y; o3.z += a3 * w.z; o3.w += a3 * w.w;
  }
  float4* out4 = (float4*)(out_v + (size_t)(row0 + ty * 4) * DIM);
  out4[0 * 32 + tx] = o0;
  out4[1 * 32 + tx] = o1;
  out4[2 * 32 + tx] = o2;
  out4[3 * 32 + tx] = o3;
}

extern "C" void kernel_launch(void* const* d_in, const int* in_sizes, int n_in,
                              void* d_out, int out_size, void* d_ws, size_t ws_size,
                              hipStream_t stream) {
  const float* x      = (const float*)d_in[0];
  const float* inc    = (const float*)d_in[1];
  const int*   orders = (const int*)d_in[2];
  const float* norm   = (const float*)d_in[3];
  const float* W      = (const float*)d_in[4];
  const float* Bb     = (const float*)d_in[5];
  float* out_v = (float*)d_out;
  float* out_e = (float*)d_out + (size_t)NN * DIM;

  char* ws = (char*)d_ws;
  uint16_t* xhi   = (uint16_t*)(ws + WS_XHI);
  float* colsum   = (float*)(ws + WS_COLSUM);
  float* c0e      = (float*)(ws + WS_C0E);
  int*   elist    = (int*)(ws + WS_ELIST);
  float* part     = (float*)(ws + WS_PART);

  k_prep<<<128, 256, 0, stream>>>(x, xhi, colsum);
  k_c0e<<<NL, 128, 0, stream>>>(colsum, W, Bb, c0e);
  k_count<<<1, 256, 0, stream>>>(orders, elist);
  k_gemm<<<512, 256, 0, stream>>>(inc, xhi, part);
  k_edgeG<<<NE / EPB, 128, 0, stream>>>(part, elist, orders, norm, W, c0e, out_e);
  k_node<<<NN / 32, 256, 0, stream>>>(x, W, c0e, out_v);
}

// Round 12
// 121.174 us; speedup vs baseline: 1.2149x; 1.0496x over previous
//
#include <hip/hip_runtime.h>
#include <stdint.h>

#define NN 8192   // nodes
#define NE 8192   // edges
#define DIM 128
#define NL 17
#define SPLITK 8
#define KCHUNK (NN / SPLITK)   // 1024
#define NIT (KCHUNK / 32)      // 32

typedef float f32x4 __attribute__((ext_vector_type(4)));
typedef short short8 __attribute__((ext_vector_type(8)));

// ---- workspace layout (bytes) ----
#define WS_XHI    0ull                              // 2 MB  (xT blocked bf16)
#define WS_COLSUM (4ull << 20)                      // 64 KB (128 x 128 f32)
#define WS_C0E    ((4ull << 20) + (64ull << 10))    // 8.5 KB
#define WS_PART   (8ull << 20)                      // 32 MB (SPLITK x E x D f32)

#define GPTR(p) ((const __attribute__((address_space(1))) uint32_t*)(p))
#define LPTR(p) ((__attribute__((address_space(3))) uint32_t*)(p))

// Round-to-nearest-even f32 -> bf16 bits.
__device__ __forceinline__ uint16_t f32_to_bf16(float v) {
  uint32_t u = __builtin_bit_cast(uint32_t, v);
  u += 0x7fffu + ((u >> 16) & 1u);
  return (uint16_t)(u >> 16);
}

// Prep: column sums of x (for x0), and x transposed into k-blocked bf16:
// xhi[kblk][d][kk] with kblk = k/32, kk = k%32. 128 blocks x 64 nodes.
__global__ __launch_bounds__(256) void k_prep(const float* __restrict__ x,
                                              uint16_t* __restrict__ xhi,
                                              float* __restrict__ colsum) {
  __shared__ float xs[64][129];
  const int t = threadIdx.x;
  const int b = blockIdx.x;  // nodes b*64 .. b*64+63
  const float4* xg = (const float4*)(x + (size_t)b * 64 * DIM);
  for (int r = 0; r < 8; ++r) {
    int f = t + r * 256;           // float4 index within tile
    float4 v = xg[f];
    int n = f >> 5;
    int d0 = (f & 31) * 4;
    xs[n][d0] = v.x; xs[n][d0 + 1] = v.y; xs[n][d0 + 2] = v.z; xs[n][d0 + 3] = v.w;
  }
  __syncthreads();
  if (t < 128) {
    float s = 0.f;
    for (int n = 0; n < 64; ++n) s += xs[n][t];
    colsum[b * DIM + t] = s;
  }
  // 1024 16B chunks: q = [kb(1)][d(7)][c(2)]
  for (int r = 0; r < 4; ++r) {
    int q = t + r * 256;
    int c = q & 3;
    int d = (q >> 2) & 127;
    int kb = q >> 9;
    int kk0 = c * 8;
    uint32_t w[4];
    for (int j = 0; j < 4; ++j) {
      uint16_t h0 = f32_to_bf16(xs[kb * 32 + kk0 + 2 * j][d]);
      uint16_t h1 = f32_to_bf16(xs[kb * 32 + kk0 + 2 * j + 1][d]);
      w[j] = (uint32_t)h0 | ((uint32_t)h1 << 16);
    }
    int kblk = b * 2 + kb;
    uint16_t* dst = xhi + ((size_t)(kblk * 128 + d)) * 32 + kk0;
    *(uint4*)dst = make_uint4(w[0], w[1], w[2], w[3]);
  }
}

// c0e[l][j] = x0 @ W[0,l] + B[l]; c0e[1] doubles as node-side constant.
__global__ __launch_bounds__(128) void k_c0e(const float* __restrict__ colsum,
                                             const float* __restrict__ W,
                                             const float* __restrict__ Bb,
                                             float* __restrict__ c0e) {
  __shared__ float x0[DIM];
  const int j = threadIdx.x;
  float s = 0.f;
  for (int b = 0; b < 128; ++b) s += colsum[b * DIM + j];
  x0[j] = s * (1.0f / NN);
  __syncthreads();
  const int l = blockIdx.x;
  const float* W0l = W + (size_t)l * DIM * DIM;
  float acc = Bb[l * DIM + j];
#pragma unroll 8
  for (int i = 0; i < DIM; ++i) acc += x0[i] * W0l[(size_t)i * DIM + j];
  c0e[l * DIM + j] = acc;
}

// Big MFMA GEMM: part[s][e][d] = sum_{k in chunk s} inc[k][e] * xhi[k][d].
// BM=64 re-tile of the proven round-7 structure: 1024 blocks, 4 blocks/CU
// (16 waves/CU) so the per-iteration barrier drain of the A-stream is
// covered by 4 independent block streams. Per-(e,d) arithmetic identical.
__global__ __launch_bounds__(256, 4) void k_gemm(const float* __restrict__ inc,
                                                 const uint16_t* __restrict__ xhi,
                                                 float* __restrict__ part) {
  __shared__ uint16_t Bs[2][4096];   // 8 KB per buffer
  const int t = threadIdx.x;
  const int mb = blockIdx.x & 127;   // 128 M-tiles of 64 edges
  const int s = blockIdx.x >> 7;     // 8 splits
  const int e0 = mb * 64;
  const int w = t >> 6;
  const int lane = t & 63;
  const int lm = lane & 15;
  const int lk = lane >> 4;          // 0..3
  const int kbase = s * KCHUNK;
  const int kb0 = kbase >> 5;        // first kblk

  f32x4 acc[8];
#pragma unroll
  for (int b = 0; b < 8; ++b) acc[b] = (f32x4){0.f, 0.f, 0.f, 0.f};

  const char* hbase = (const char*)xhi;

#define STAGE(buf, kblk) { \
    const char* hsrc = hbase + (size_t)(kblk) * 8192; \
    char* dbase = (char*)&Bs[buf][0]; \
    _Pragma("unroll") \
    for (int j = 0; j < 2; ++j) { \
      int q = w + 4 * j; \
      __builtin_amdgcn_global_load_lds(GPTR(hsrc + q * 1024 + lane * 16), \
                                       LPTR(dbase + q * 1024), 16, 0, 0); \
    } }

#define LOADA(u, it) { \
    const int k0_ = kbase + (it) * 32; \
    const float* ap = inc + (size_t)(k0_ + lk * 8) * NE + (e0 + w * 16 + lm); \
    _Pragma("unroll") \
    for (int j = 0; j < 8; ++j) \
      u[j] = __builtin_bit_cast(uint32_t, ap[(size_t)j * NE]); \
  }

#define COMPUTE(buf, u) { \
    short8 afr; \
    { \
      union { uint32_t w4[4]; short8 s8; } pk; \
      _Pragma("unroll") \
      for (int j = 0; j < 4; ++j) \
        pk.w4[j] = (u[2 * j + 1] & 0xffff0000u) | (u[2 * j] >> 16); \
      afr = pk.s8; \
    } \
    _Pragma("unroll") \
    for (int fn = 0; fn < 8; ++fn) { \
      int n = fn * 16 + lm; \
      short8 bh = *(const short8*)&Bs[buf][n * 32 + lk * 8]; \
      acc[fn] = __builtin_amdgcn_mfma_f32_16x16x32_bf16(afr, bh, acc[fn], 0, 0, 0); \
    } }

  uint32_t ua[8], ub[8];
  STAGE(0, kb0);
  LOADA(ua, 0);
  __syncthreads();               // Bs[0] staged, ua ready

  for (int it2 = 0; it2 < NIT; it2 += 2) {
    if (it2 + 1 < NIT) { STAGE(1, kb0 + it2 + 1); LOADA(ub, it2 + 1); }
    COMPUTE(0, ua);
    __syncthreads();
    if (it2 + 2 < NIT) { STAGE(0, kb0 + it2 + 2); LOADA(ua, it2 + 2); }
    COMPUTE(1, ub);
    __syncthreads();
  }

  float* pbase = part + (size_t)s * NE * DIM;
#pragma unroll
  for (int fn = 0; fn < 8; ++fn)
#pragma unroll
    for (int r = 0; r < 4; ++r) {
      int e = e0 + w * 16 + lk * 4 + r;
      int d = fn * 16 + lm;
      pbase[(size_t)e * DIM + d] = acc[fn][r];
    }
#undef STAGE
#undef LOADA
#undef COMPUTE
}

// Per-edge: reduce split-K partials, normalize, matvec with W[1,order] + c0e.
__global__ __launch_bounds__(128) void k_edge2(const float* __restrict__ part,
                                               const int* __restrict__ orders,
                                               const float* __restrict__ norm,
                                               const float* __restrict__ W,
                                               const float* __restrict__ c0e,
                                               float* __restrict__ out_e) {
  __shared__ float xl[DIM];
  const int t = threadIdx.x;
  const int e = blockIdx.x;
  float s = 0.f;
#pragma unroll
  for (int k = 0; k < SPLITK; ++k)
    s += part[(size_t)k * NE * DIM + (size_t)e * DIM + t];
  xl[t] = s / norm[e];
  __syncthreads();
  const int l = orders[e];
  const float* W1l = W + (size_t)(NL + l) * DIM * DIM;
  float o = c0e[l * DIM + t];
#pragma unroll 8
  for (int i = 0; i < DIM; ++i) o += xl[i] * W1l[(size_t)i * DIM + t];
  out_e[(size_t)e * DIM + t] = o;
}

// Node side: out_v[n] = c0e[1] + x[n] @ W[1,1]. 4x4 register tile per thread.
__global__ __launch_bounds__(256) void k_node(const float* __restrict__ x,
                                              const float* __restrict__ W,
                                              const float* __restrict__ c0e,
                                              float* __restrict__ out_v) {
  __shared__ float xr[32][DIM];
  const int t = threadIdx.x;
  const int row0 = blockIdx.x * 32;
  for (int i = t; i < 32 * DIM; i += 256)
    xr[i >> 7][i & 127] = x[(size_t)row0 * DIM + i];
  const int tx = t & 31;
  const int ty = t >> 5;
  const float4* W4 = (const float4*)(W + (size_t)(NL + 1) * DIM * DIM);
  const float4 cv = ((const float4*)(c0e + DIM))[tx];
  float4 o0 = cv, o1 = cv, o2 = cv, o3 = cv;
  __syncthreads();
#pragma unroll 4
  for (int k = 0; k < DIM; ++k) {
    float4 w = W4[k * 32 + tx];
    float a0 = xr[ty * 4 + 0][k];
    float a1 = xr[ty * 4 + 1][k];
    float a2 = xr[ty * 4 + 2][k];
    float a3 = xr[ty * 4 + 3][k];
    o0.x += a0 * w.x; o0.y += a0 * w.y; o0.z += a0 * w.z; o0.w += a0 * w.w;
    o1.x += a1 * w.x; o1.y += a1 * w.y; o1.z += a1 * w.z; o1.w += a1 * w.w;
    o2.x += a2 * w.x; o2.y += a2 * w.y; o2.z += a2 * w.z; o2.w += a2 * w.w;
    o3.x += a3 * w.x; o3.y += a3 * w.y; o3.z += a3 * w.z; o3.w += a3 * w.w;
  }
  float4* out4 = (float4*)(out_v + (size_t)(row0 + ty * 4) * DIM);
  out4[0 * 32 + tx] = o0;
  out4[1 * 32 + tx] = o1;
  out4[2 * 32 + tx] = o2;
  out4[3 * 32 + tx] = o3;
}

extern "C" void kernel_launch(void* const* d_in, const int* in_sizes, int n_in,
                              void* d_out, int out_size, void* d_ws, size_t ws_size,
                              hipStream_t stream) {
  const float* x      = (const float*)d_in[0];
  const float* inc    = (const float*)d_in[1];
  const int*   orders = (const int*)d_in[2];
  const float* norm   = (const float*)d_in[3];
  const float* W      = (const float*)d_in[4];
  const float* Bb     = (const float*)d_in[5];
  float* out_v = (float*)d_out;
  float* out_e = (float*)d_out + (size_t)NN * DIM;

  char* ws = (char*)d_ws;
  uint16_t* xhi   = (uint16_t*)(ws + WS_XHI);
  float* colsum   = (float*)(ws + WS_COLSUM);
  float* c0e      = (float*)(ws + WS_C0E);
  float* part     = (float*)(ws + WS_PART);

  k_prep<<<128, 256, 0, stream>>>(x, xhi, colsum);
  k_c0e<<<NL, 128, 0, stream>>>(colsum, W, Bb, c0e);
  k_gemm<<<1024, 256, 0, stream>>>(inc, xhi, part);
  k_edge2<<<NE, 128, 0, stream>>>(part, orders, norm, W, c0e, out_e);
  k_node<<<NN / 32, 256, 0, stream>>>(x, W, c0e, out_v);
}

// Round 13
// 109.162 us; speedup vs baseline: 1.3486x; 1.1100x over previous
//
#include <hip/hip_runtime.h>
#include <stdint.h>

#define NN 8192   // nodes
#define NE 8192   // edges
#define DIM 128
#define NL 17
#define SPLITK 8
#define KCHUNK (NN / SPLITK)   // 1024
#define NIT (KCHUNK / 32)      // 32

typedef float f32x4 __attribute__((ext_vector_type(4)));
typedef short short8 __attribute__((ext_vector_type(8)));

// ---- workspace layout (bytes) ----
#define WS_XHI    0ull                              // 2 MB  (xT blocked bf16)
#define WS_COLSUM (4ull << 20)                      // 64 KB (128 x 128 f32)
#define WS_C0E    ((4ull << 20) + (64ull << 10))    // 8.5 KB
#define WS_PART   (8ull << 20)                      // 32 MB (SPLITK x E x D f32)

#define GPTR(p) ((const __attribute__((address_space(1))) uint32_t*)(p))
#define LPTR(p) ((__attribute__((address_space(3))) uint32_t*)(p))

// Round-to-nearest-even f32 -> bf16 bits.
__device__ __forceinline__ uint16_t f32_to_bf16(float v) {
  uint32_t u = __builtin_bit_cast(uint32_t, v);
  u += 0x7fffu + ((u >> 16) & 1u);
  return (uint16_t)(u >> 16);
}

// Prep: column sums of x (for x0), and x transposed into k-blocked bf16:
// xhi[kblk][d][kk] with kblk = k/32, kk = k%32. 128 blocks x 64 nodes.
__global__ __launch_bounds__(256) void k_prep(const float* __restrict__ x,
                                              uint16_t* __restrict__ xhi,
                                              float* __restrict__ colsum) {
  __shared__ float xs[64][129];
  const int t = threadIdx.x;
  const int b = blockIdx.x;  // nodes b*64 .. b*64+63
  const float4* xg = (const float4*)(x + (size_t)b * 64 * DIM);
  for (int r = 0; r < 8; ++r) {
    int f = t + r * 256;           // float4 index within tile
    float4 v = xg[f];
    int n = f >> 5;
    int d0 = (f & 31) * 4;
    xs[n][d0] = v.x; xs[n][d0 + 1] = v.y; xs[n][d0 + 2] = v.z; xs[n][d0 + 3] = v.w;
  }
  __syncthreads();
  if (t < 128) {
    float s = 0.f;
    for (int n = 0; n < 64; ++n) s += xs[n][t];
    colsum[b * DIM + t] = s;
  }
  // 1024 16B chunks: q = [kb(1)][d(7)][c(2)]
  for (int r = 0; r < 4; ++r) {
    int q = t + r * 256;
    int c = q & 3;
    int d = (q >> 2) & 127;
    int kb = q >> 9;
    int kk0 = c * 8;
    uint32_t w[4];
    for (int j = 0; j < 4; ++j) {
      uint16_t h0 = f32_to_bf16(xs[kb * 32 + kk0 + 2 * j][d]);
      uint16_t h1 = f32_to_bf16(xs[kb * 32 + kk0 + 2 * j + 1][d]);
      w[j] = (uint32_t)h0 | ((uint32_t)h1 << 16);
    }
    int kblk = b * 2 + kb;
    uint16_t* dst = xhi + ((size_t)(kblk * 128 + d)) * 32 + kk0;
    *(uint4*)dst = make_uint4(w[0], w[1], w[2], w[3]);
  }
}

// c0e[l][j] = x0 @ W[0,l] + B[l]; c0e[1] doubles as node-side constant.
__global__ __launch_bounds__(128) void k_c0e(const float* __restrict__ colsum,
                                             const float* __restrict__ W,
                                             const float* __restrict__ Bb,
                                             float* __restrict__ c0e) {
  __shared__ float x0[DIM];
  const int j = threadIdx.x;
  float s = 0.f;
  for (int b = 0; b < 128; ++b) s += colsum[b * DIM + j];
  x0[j] = s * (1.0f / NN);
  __syncthreads();
  const int l = blockIdx.x;
  const float* W0l = W + (size_t)l * DIM * DIM;
  float acc = Bb[l * DIM + j];
#pragma unroll 8
  for (int i = 0; i < DIM; ++i) acc += x0[i] * W0l[(size_t)i * DIM + j];
  c0e[l * DIM + j] = acc;
}

// Big MFMA GEMM (R7 geometry): part[s][e][d] = sum_k inc[k][e]*xhi[k][d].
// T4 counted-vmcnt pipeline: raw s_barrier + s_waitcnt vmcnt(18) keeps the
// 18 just-issued next-iter loads (2 stage + 16 A) IN FLIGHT across the
// barrier; only the previous iteration's 18 drain. One sched_barrier(0)
// after each vmcnt (rule #18); nothing else pinned (m141).
__global__ __launch_bounds__(256, 2) void k_gemm(const float* __restrict__ inc,
                                                 const uint16_t* __restrict__ xhi,
                                                 float* __restrict__ part) {
  __shared__ uint16_t Bs[2][4096];   // 8 KB per buffer
  const int t = threadIdx.x;
  const int mb = blockIdx.x & 63;
  const int s = blockIdx.x >> 6;
  const int e0 = mb * 128;
  const int w = t >> 6;
  const int lane = t & 63;
  const int lm = lane & 15;
  const int lk = lane >> 4;          // 0..3
  const int kbase = s * KCHUNK;
  const int kb0 = kbase >> 5;        // first kblk

  f32x4 acc[2][8];
#pragma unroll
  for (int a = 0; a < 2; ++a)
#pragma unroll
    for (int b = 0; b < 8; ++b) acc[a][b] = (f32x4){0.f, 0.f, 0.f, 0.f};

  const char* hbase = (const char*)xhi;

#define STAGE(buf, kblk) { \
    const char* hsrc = hbase + (size_t)(kblk) * 8192; \
    char* dbase = (char*)&Bs[buf][0]; \
    _Pragma("unroll") \
    for (int j = 0; j < 2; ++j) { \
      int q = w + 4 * j; \
      __builtin_amdgcn_global_load_lds(GPTR(hsrc + q * 1024 + lane * 16), \
                                       LPTR(dbase + q * 1024), 16, 0, 0); \
    } }

#define LOADA(u, it) { \
    const int k0_ = kbase + (it) * 32; \
    _Pragma("unroll") \
    for (int fm = 0; fm < 2; ++fm) { \
      const float* ap = inc + (size_t)(k0_ + lk * 8) * NE + (e0 + w * 32 + fm * 16 + lm); \
      _Pragma("unroll") \
      for (int j = 0; j < 8; ++j) \
        u[fm][j] = __builtin_bit_cast(uint32_t, ap[(size_t)j * NE]); \
    } }

#define COMPUTE(buf, u) { \
    short8 afr[2]; \
    _Pragma("unroll") \
    for (int fm = 0; fm < 2; ++fm) { \
      union { uint32_t w4[4]; short8 s8; } pk; \
      _Pragma("unroll") \
      for (int j = 0; j < 4; ++j) \
        pk.w4[j] = (u[fm][2 * j + 1] & 0xffff0000u) | (u[fm][2 * j] >> 16); \
      afr[fm] = pk.s8; \
    } \
    _Pragma("unroll") \
    for (int fn = 0; fn < 8; ++fn) { \
      int n = fn * 16 + lm; \
      short8 bh = *(const short8*)&Bs[buf][n * 32 + lk * 8]; \
      acc[0][fn] = __builtin_amdgcn_mfma_f32_16x16x32_bf16(afr[0], bh, acc[0][fn], 0, 0, 0); \
      acc[1][fn] = __builtin_amdgcn_mfma_f32_16x16x32_bf16(afr[1], bh, acc[1][fn], 0, 0, 0); \
    } }

#define BAR() __builtin_amdgcn_s_barrier()
#define WAITK() { asm volatile("s_waitcnt vmcnt(18)" ::: "memory"); \
                  __builtin_amdgcn_sched_barrier(0); }
#define WAIT0() { asm volatile("s_waitcnt vmcnt(0)" ::: "memory"); \
                  __builtin_amdgcn_sched_barrier(0); }

  uint32_t ua[2][8], ub[2][8];
  STAGE(0, kb0);
  LOADA(ua, 0);

  for (int it2 = 0; it2 < NIT; it2 += 2) {
    // even half: compute Bs[0]/ua, prefetch Bs[1]/ub
    if (it2 + 1 < NIT) { STAGE(1, kb0 + it2 + 1); LOADA(ub, it2 + 1); WAITK(); }
    else { WAIT0(); }
    BAR();                       // all waves' stage(0) drained -> Bs[0] ready
    COMPUTE(0, ua);
    BAR();                       // all waves done reading Bs[0]
    // odd half: compute Bs[1]/ub, prefetch Bs[0]/ua
    if (it2 + 2 < NIT) { STAGE(0, kb0 + it2 + 2); LOADA(ua, it2 + 2); WAITK(); }
    else { WAIT0(); }
    BAR();                       // Bs[1] ready
    COMPUTE(1, ub);
    BAR();                       // done reading Bs[1]
  }

  float* pbase = part + (size_t)s * NE * DIM;
#pragma unroll
  for (int fm = 0; fm < 2; ++fm)
#pragma unroll
    for (int fn = 0; fn < 8; ++fn)
#pragma unroll
      for (int r = 0; r < 4; ++r) {
        int e = e0 + w * 32 + fm * 16 + lk * 4 + r;
        int d = fn * 16 + lm;
        pbase[(size_t)e * DIM + d] = acc[fm][fn][r];
      }
#undef STAGE
#undef LOADA
#undef COMPUTE
#undef BAR
#undef WAITK
#undef WAIT0
}

// Per-edge: reduce split-K partials, normalize, matvec with W[1,order] + c0e.
__global__ __launch_bounds__(128) void k_edge2(const float* __restrict__ part,
                                               const int* __restrict__ orders,
                                               const float* __restrict__ norm,
                                               const float* __restrict__ W,
                                               const float* __restrict__ c0e,
                                               float* __restrict__ out_e) {
  __shared__ float xl[DIM];
  const int t = threadIdx.x;
  const int e = blockIdx.x;
  float s = 0.f;
#pragma unroll
  for (int k = 0; k < SPLITK; ++k)
    s += part[(size_t)k * NE * DIM + (size_t)e * DIM + t];
  xl[t] = s / norm[e];
  __syncthreads();
  const int l = orders[e];
  const float* W1l = W + (size_t)(NL + l) * DIM * DIM;
  float o = c0e[l * DIM + t];
#pragma unroll 8
  for (int i = 0; i < DIM; ++i) o += xl[i] * W1l[(size_t)i * DIM + t];
  out_e[(size_t)e * DIM + t] = o;
}

// Node side: out_v[n] = c0e[1] + x[n] @ W[1,1]. 4x4 register tile per thread.
__global__ __launch_bounds__(256) void k_node(const float* __restrict__ x,
                                              const float* __restrict__ W,
                                              const float* __restrict__ c0e,
                                              float* __restrict__ out_v) {
  __shared__ float xr[32][DIM];
  const int t = threadIdx.x;
  const int row0 = blockIdx.x * 32;
  for (int i = t; i < 32 * DIM; i += 256)
    xr[i >> 7][i & 127] = x[(size_t)row0 * DIM + i];
  const int tx = t & 31;
  const int ty = t >> 5;
  const float4* W4 = (const float4*)(W + (size_t)(NL + 1) * DIM * DIM);
  const float4 cv = ((const float4*)(c0e + DIM))[tx];
  float4 o0 = cv, o1 = cv, o2 = cv, o3 = cv;
  __syncthreads();
#pragma unroll 4
  for (int k = 0; k < DIM; ++k) {
    float4 w = W4[k * 32 + tx];
    float a0 = xr[ty * 4 + 0][k];
    float a1 = xr[ty * 4 + 1][k];
    float a2 = xr[ty * 4 + 2][k];
    float a3 = xr[ty * 4 + 3][k];
    o0.x += a0 * w.x; o0.y += a0 * w.y; o0.z += a0 * w.z; o0.w += a0 * w.w;
    o1.x += a1 * w.x; o1.y += a1 * w.y; o1.z += a1 * w.z; o1.w += a1 * w.w;
    o2.x += a2 * w.x; o2.y += a2 * w.y; o2.z += a2 * w.z; o2.w += a2 * w.w;
    o3.x += a3 * w.x; o3.y += a3 * w.y; o3.z += a3 * w.z; o3.w += a3 * w.w;
  }
  float4* out4 = (float4*)(out_v + (size_t)(row0 + ty * 4) * DIM);
  out4[0 * 32 + tx] = o0;
  out4[1 * 32 + tx] = o1;
  out4[2 * 32 + tx] = o2;
  out4[3 * 32 + tx] = o3;
}

extern "C" void kernel_launch(void* const* d_in, const int* in_sizes, int n_in,
                              void* d_out, int out_size, void* d_ws, size_t ws_size,
                              hipStream_t stream) {
  const float* x      = (const float*)d_in[0];
  const float* inc    = (const float*)d_in[1];
  const int*   orders = (const int*)d_in[2];
  const float* norm   = (const float*)d_in[3];
  const float* W      = (const float*)d_in[4];
  const float* Bb     = (const float*)d_in[5];
  float* out_v = (float*)d_out;
  float* out_e = (float*)d_out + (size_t)NN * DIM;

  char* ws = (char*)d_ws;
  uint16_t* xhi   = (uint16_t*)(ws + WS_XHI);
  float* colsum   = (float*)(ws + WS_COLSUM);
  float* c0e      = (float*)(ws + WS_C0E);
  float* part     = (float*)(ws + WS_PART);

  k_prep<<<128, 256, 0, stream>>>(x, xhi, colsum);
  k_c0e<<<NL, 128, 0, stream>>>(colsum, W, Bb, c0e);
  k_gemm<<<512, 256, 0, stream>>>(inc, xhi, part);
  k_edge2<<<NE, 128, 0, stream>>>(part, orders, norm, W, c0e, out_e);
  k_node<<<NN / 32, 256, 0, stream>>>(x, W, c0e, out_v);
}